// Round 3
// baseline (154.247 us; speedup 1.0000x reference)
//
#include <hip/hip_runtime.h>
#include <hip/hip_bf16.h>

#define N_ROWS 8192
#define DIM 256
#define NANCH 64
#define NVIEW 128
#define BM 32
#define NWAVE 16

typedef __attribute__((ext_vector_type(8))) short bf16x8;
typedef __attribute__((ext_vector_type(4))) float f32x4;
typedef __attribute__((ext_vector_type(4))) float float4v;
typedef __attribute__((ext_vector_type(4))) unsigned short ushort4v;

__device__ __forceinline__ unsigned short f2bf(float x) {
  union { float f; unsigned int u; } c; c.f = x;
  unsigned int u = c.u;
  unsigned int r = (u + 0x7fffu + ((u >> 16) & 1u)) >> 16;
  return (unsigned short)r;
}

__device__ __forceinline__ float bf2f(unsigned short b) {
  union { unsigned int u; float f; } c; c.u = ((unsigned int)b) << 16;
  return c.f;
}

// fp32 -> bf16 with 1/sqrt(T) prescale, fused with per-row squared-norm
// (= the Gram diagonal = the row max of the logits). One wave per row.
__global__ void cast_diag_kernel(const float4v* __restrict__ in,
                                 ushort4v* __restrict__ out,
                                 float* __restrict__ diag) {
  const int w = threadIdx.x >> 6;
  const int l = threadIdx.x & 63;
  const int row = blockIdx.x * 4 + w;
  const float s = 3.16227766016838f; // 1/sqrt(0.1)
  float4v v = in[row * 64 + l];
  ushort4v o;
  o.x = f2bf(v.x * s);
  o.y = f2bf(v.y * s);
  o.z = f2bf(v.z * s);
  o.w = f2bf(v.w * s);
  out[row * 64 + l] = o;
  // squared norm of the ROUNDED values (matches MFMA's diagonal exactly)
  float c0 = bf2f(o.x), c1 = bf2f(o.y), c2 = bf2f(o.z), c3 = bf2f(o.w);
  float ss = c0 * c0 + c1 * c1 + c2 * c2 + c3 * c3;
#pragma unroll
  for (int st = 1; st < 64; st <<= 1) ss += __shfl_xor(ss, st);
  if (l == 0) diag[row] = ss;
}

// 1024-thread blocks (16 waves), 1 block/CU, 4 waves/SIMD, VGPR cap 128 so
// the 64-VGPR A-fragment set stays register-resident (round-2 had remat at 64).
__global__ __launch_bounds__(1024, 4) void pcl_main(const unsigned short* __restrict__ Xb,
                                                    const int* __restrict__ labels,
                                                    const float* __restrict__ diag,
                                                    float* __restrict__ partials) {
  const int blk = blockIdx.x;          // 0..255
  const int r0 = blk * BM;             // global row start (32 rows per block)
  const int tid = threadIdx.x;
  const int wid = tid >> 6;            // 0..15
  const int lane = tid & 63;
  const int lo = lane & 15;
  const int hi = lane >> 4;
  const int cq = wid & 3;              // column quarter (32 cols)
  const int bq = wid >> 2;             // anchor phase 0..3

  __shared__ int slab[NANCH];
  __shared__ float sm[NWAVE][BM];
  __shared__ float sns[NWAVE][BM];
  __shared__ float smf[BM];
  __shared__ float snsf[BM];
  __shared__ float sdiag[BM];
  __shared__ int poslist[NANCH];
  __shared__ int scnt;

  if (tid < NANCH) slab[tid] = labels[tid];
  if (tid >= NANCH && tid < NANCH + BM) sdiag[tid - NANCH] = diag[r0 + tid - NANCH];
  __syncthreads();
  const int La = slab[r0 >> 7];

  // Hoist A fragments (this block's 32 rows, all K=256) into registers.
  // Lane holds 8 contiguous k at k-offset (lane>>4)*8, row = lane&15.
  bf16x8 afrag[2][8];
#pragma unroll
  for (int ri = 0; ri < 2; ++ri) {
#pragma unroll
    for (int ks = 0; ks < 8; ++ks) {
      const unsigned short* p = Xb + (r0 + ri * 16 + lo) * DIM + ks * 32 + hi * 8;
      afrag[ri][ks] = *(const bf16x8*)p;
    }
  }

  // Per-lane online state; m starts at the TRUE row max (the Gram diagonal),
  // so the update branch below fires only on the own-anchor tile (T13 defer).
  float m[8], ns[8];
#pragma unroll
  for (int ri = 0; ri < 2; ++ri)
#pragma unroll
    for (int reg = 0; reg < 4; ++reg) {
      m[ri * 4 + reg] = sdiag[ri * 16 + hi * 4 + reg];
      ns[ri * 4 + reg] = 0.f;
    }

  // ---------------- Pass 1: negative-exp sum (max known) ----------------
  for (int j = 0; j < NANCH / 4; ++j) {
    const int b = bq + 4 * j;
    const bool isneg = (slab[b] != La);
    const int c0 = b * NVIEW + cq * 32;
    f32x4 acc[2][2];
#pragma unroll
    for (int ri = 0; ri < 2; ++ri)
#pragma unroll
      for (int ci = 0; ci < 2; ++ci)
        acc[ri][ci] = (f32x4){0.f, 0.f, 0.f, 0.f};

#pragma unroll
    for (int ks = 0; ks < 8; ++ks) {
      bf16x8 b0 = *(const bf16x8*)(Xb + (c0 + lo) * DIM + ks * 32 + hi * 8);
      bf16x8 b1 = *(const bf16x8*)(Xb + (c0 + 16 + lo) * DIM + ks * 32 + hi * 8);
      acc[0][0] = __builtin_amdgcn_mfma_f32_16x16x32_bf16(afrag[0][ks], b0, acc[0][0], 0, 0, 0);
      acc[0][1] = __builtin_amdgcn_mfma_f32_16x16x32_bf16(afrag[0][ks], b1, acc[0][1], 0, 0, 0);
      acc[1][0] = __builtin_amdgcn_mfma_f32_16x16x32_bf16(afrag[1][ks], b0, acc[1][0], 0, 0, 0);
      acc[1][1] = __builtin_amdgcn_mfma_f32_16x16x32_bf16(afrag[1][ks], b1, acc[1][1], 0, 0, 0);
    }

#pragma unroll
    for (int ri = 0; ri < 2; ++ri) {
#pragma unroll
      for (int reg = 0; reg < 4; ++reg) {
        const int t = ri * 4 + reg;
        float v0 = acc[ri][0][reg];
        float v1 = acc[ri][1][reg];
        float tm = fmaxf(v0, v1);
        // rare path: tile within exp() range of the row max (own-anchor only)
        if (__builtin_expect(tm > m[t] - 40.f, 0)) {
          float mn = fmaxf(m[t], tm);
          float scale = __expf(m[t] - mn);
          float add = isneg ? (__expf(v0 - mn) + __expf(v1 - mn)) : 0.f;
          ns[t] = ns[t] * scale + add;
          m[t] = mn;
        }
      }
    }
  }

  // Combine (m, ns) across the 16-lane column groups within the wave.
#pragma unroll
  for (int t = 0; t < 8; ++t) {
#pragma unroll
    for (int st = 1; st < 16; st <<= 1) {
      float mo = __shfl_xor(m[t], st);
      float no = __shfl_xor(ns[t], st);
      float mn = fmaxf(m[t], mo);
      ns[t] = ns[t] * __expf(m[t] - mn) + no * __expf(mo - mn);
      m[t] = mn;
    }
  }

  // Stash per-wave (m, ns) in LDS.
  if (lo == 0) {
#pragma unroll
    for (int ri = 0; ri < 2; ++ri)
#pragma unroll
      for (int reg = 0; reg < 4; ++reg) {
        int row = ri * 16 + hi * 4 + reg;
        sm[wid][row] = m[ri * 4 + reg];
        sns[wid][row] = ns[ri * 4 + reg];
      }
  }
  // Build positive-anchor list concurrently.
  if (tid == 0) {
    int c = 0;
    for (int b = 0; b < NANCH; ++b)
      if (slab[b] == La) poslist[c++] = b;
    scnt = c;
  }
  __syncthreads();

  // Merge across 16 waves -> final per-row (max, negsum) in LDS.
  if (tid < BM) {
    float M = -1e30f;
#pragma unroll
    for (int w = 0; w < NWAVE; ++w) M = fmaxf(M, sm[w][tid]);
    float NS = 0.f;
#pragma unroll
    for (int w = 0; w < NWAVE; ++w) NS += sns[w][tid] * __expf(sm[w][tid] - M);
    smf[tid] = M;
    snsf[tid] = NS;
  }
  __syncthreads();
  const int cnt = scnt;

  // ---------------- Pass 2: positives only ----------------
  float pos[8];
#pragma unroll
  for (int t = 0; t < 8; ++t) pos[t] = 0.f;

  for (int p = bq; p < cnt; p += 4) {
    const int b = poslist[p];
    const int c0 = b * NVIEW + cq * 32;
    f32x4 acc[2][2];
#pragma unroll
    for (int ri = 0; ri < 2; ++ri)
#pragma unroll
      for (int ci = 0; ci < 2; ++ci)
        acc[ri][ci] = (f32x4){0.f, 0.f, 0.f, 0.f};

#pragma unroll
    for (int ks = 0; ks < 8; ++ks) {
      bf16x8 b0 = *(const bf16x8*)(Xb + (c0 + lo) * DIM + ks * 32 + hi * 8);
      bf16x8 b1 = *(const bf16x8*)(Xb + (c0 + 16 + lo) * DIM + ks * 32 + hi * 8);
      acc[0][0] = __builtin_amdgcn_mfma_f32_16x16x32_bf16(afrag[0][ks], b0, acc[0][0], 0, 0, 0);
      acc[0][1] = __builtin_amdgcn_mfma_f32_16x16x32_bf16(afrag[0][ks], b1, acc[0][1], 0, 0, 0);
      acc[1][0] = __builtin_amdgcn_mfma_f32_16x16x32_bf16(afrag[1][ks], b0, acc[1][0], 0, 0, 0);
      acc[1][1] = __builtin_amdgcn_mfma_f32_16x16x32_bf16(afrag[1][ks], b1, acc[1][1], 0, 0, 0);
    }

#pragma unroll
    for (int ri = 0; ri < 2; ++ri) {
#pragma unroll
      for (int ci = 0; ci < 2; ++ci) {
#pragma unroll
        for (int reg = 0; reg < 4; ++reg) {
          const int t = ri * 4 + reg;
          const int row = ri * 16 + hi * 4 + reg;
          int grow = r0 + row;
          int gcol = c0 + ci * 16 + lo;
          if (grow != gcol) {  // exclude diagonal
            float d = acc[ri][ci][reg] - smf[row];
            pos[t] += d - __logf(__expf(d) + snsf[row] + 1e-10f);
          }
        }
      }
    }
  }

  // Sum pos across 16-lane groups.
#pragma unroll
  for (int t = 0; t < 8; ++t) {
#pragma unroll
    for (int st = 1; st < 16; st <<= 1) pos[t] += __shfl_xor(pos[t], st);
  }

  __syncthreads();  // protect sm reuse
  if (lo == 0) {
#pragma unroll
    for (int ri = 0; ri < 2; ++ri)
#pragma unroll
      for (int reg = 0; reg < 4; ++reg) {
        int row = ri * 16 + hi * 4 + reg;
        sm[wid][row] = pos[ri * 4 + reg];
      }
  }
  __syncthreads();

  // positive count per row (uniform per block): 128 * cnt - 1
  const float poscnt = (float)(cnt * NVIEW - 1);

  if (tid < BM) {
    float P = 0.f;
#pragma unroll
    for (int w = 0; w < NWAVE; ++w) P += sm[w][tid];
    smf[tid] = P / poscnt;
  }
  __syncthreads();
  if (tid == 0) {
    float s = 0.f;
    for (int r = 0; r < BM; ++r) s += smf[r];
    partials[blk] = s;
  }
}

__global__ void final_reduce(const float* __restrict__ partials, float* __restrict__ out) {
  __shared__ float s[256];
  int t = threadIdx.x;
  s[t] = partials[t];
  __syncthreads();
  for (int st = 128; st > 0; st >>= 1) {
    if (t < st) s[t] += s[t + st];
    __syncthreads();
  }
  if (t == 0) {
    // loss = mean over N rows of -(T/BASE_T) * mean_log_prob_pos
    out[0] = -(0.1f / 0.07f) * s[0] / (float)N_ROWS;
  }
}

extern "C" void kernel_launch(void* const* d_in, const int* in_sizes, int n_in,
                              void* d_out, int out_size, void* d_ws, size_t ws_size,
                              hipStream_t stream) {
  const float* feats = (const float*)d_in[0];
  const int* labels = (const int*)d_in[1];
  float* out = (float*)d_out;

  unsigned short* Xb = (unsigned short*)d_ws;                  // 4 MB
  float* diag = (float*)((char*)d_ws + (size_t)N_ROWS * DIM * 2);      // 32 KB
  float* partials = (float*)((char*)d_ws + (size_t)N_ROWS * DIM * 2 + N_ROWS * 4);

  cast_diag_kernel<<<N_ROWS / 4, 256, 0, stream>>>((const float4v*)feats,
                                                   (ushort4v*)Xb, diag);
  pcl_main<<<N_ROWS / BM, 1024, 0, stream>>>(Xb, labels, diag, partials);
  final_reduce<<<1, 256, 0, stream>>>(partials, out);
}

// Round 4
// 79.308 us; speedup vs baseline: 1.9449x; 1.9449x over previous
//
#include <hip/hip_runtime.h>
#include <hip/hip_bf16.h>

#define N_ROWS 8192
#define DIM 256
#define NANCH 64
#define NVIEW 128
#define NSTRIP 4
#define APS 16   // anchors per strip

typedef __attribute__((ext_vector_type(8))) short bf16x8;
typedef __attribute__((ext_vector_type(4))) float f32x4;
typedef __attribute__((ext_vector_type(4))) float float4v;
typedef __attribute__((ext_vector_type(4))) unsigned short ushort4v;

__device__ __forceinline__ unsigned short f2bf(float x) {
  union { float f; unsigned int u; } c; c.f = x;
  unsigned int u = c.u;
  unsigned int r = (u + 0x7fffu + ((u >> 16) & 1u)) >> 16;
  return (unsigned short)r;
}

__device__ __forceinline__ float bf2f(unsigned short b) {
  union { unsigned int u; float f; } c; c.u = ((unsigned int)b) << 16;
  return c.f;
}

__device__ __forceinline__ void gload_lds16(const void* g, void* l) {
  __builtin_amdgcn_global_load_lds(
      (const __attribute__((address_space(1))) unsigned int*)g,
      (__attribute__((address_space(3))) unsigned int*)l, 16, 0, 0);
}

// fp32 -> bf16 with 1/sqrt(T) prescale, fused with per-row squared-norm
// (= the Gram diagonal = the row max of the logits). One wave per row.
__global__ void cast_diag_kernel(const float4v* __restrict__ in,
                                 ushort4v* __restrict__ out,
                                 float* __restrict__ diag) {
  const int w = threadIdx.x >> 6;
  const int l = threadIdx.x & 63;
  const int row = blockIdx.x * 4 + w;
  const float s = 3.16227766016838f; // 1/sqrt(0.1)
  float4v v = in[row * 64 + l];
  ushort4v o;
  o.x = f2bf(v.x * s);
  o.y = f2bf(v.y * s);
  o.z = f2bf(v.z * s);
  o.w = f2bf(v.w * s);
  out[row * 64 + l] = o;
  float c0 = bf2f(o.x), c1 = bf2f(o.y), c2 = bf2f(o.z), c3 = bf2f(o.w);
  float ss = c0 * c0 + c1 * c1 + c2 * c2 + c3 * c3;
#pragma unroll
  for (int st = 1; st < 64; st <<= 1) ss += __shfl_xor(ss, st);
  if (l == 0) diag[row] = ss;
}

// -------- Kernel 2: negative-exp-sum partials over a (128-row x 2048-col) tile.
// grid = 64 row-blocks x 4 col-strips. 16 waves = 4 row-groups x 4 col-groups.
// B anchor tiles staged in LDS (double-buffered, pre-swizzled source so the
// swizzled ds_read_b128 is conflict-free). Max is KNOWN (= diag), so strip
// partials combine by pure addition.
__global__ __launch_bounds__(1024, 4) void pcl_negsum(
    const unsigned short* __restrict__ Xb, const int* __restrict__ labels,
    const float* __restrict__ diag, float* __restrict__ ns_partial) {
  const int rb = blockIdx.x & 63;      // row anchor (128 rows, uniform label)
  const int strip = blockIdx.x >> 6;   // 0..3 -> anchors strip*16 .. +15
  const int tid = threadIdx.x;
  const int wid = tid >> 6;
  const int lane = tid & 63;
  const int lo = lane & 15;
  const int hi = lane >> 4;
  const int rg = wid >> 2;             // row group (32 rows)
  const int cg = wid & 3;              // col group (32 cols)

  __shared__ unsigned short buf[2][NVIEW * DIM];  // 2 x 64 KB
  __shared__ float sns[16][32];
  __shared__ float sdiag[128];
  __shared__ int slab[NANCH];

  if (tid < NANCH) slab[tid] = labels[tid];
  if (tid >= 128 && tid < 256) sdiag[tid - 128] = diag[rb * 128 + tid - 128];
  __syncthreads();
  const int myLab = slab[rb];

  // A fragments: rows rb*128 + rg*32 + ri*16 + lo, k = ks*32 + hi*8. Pinned.
  bf16x8 afrag[2][8];
#pragma unroll
  for (int ri = 0; ri < 2; ++ri) {
#pragma unroll
    for (int ks = 0; ks < 8; ++ks) {
      const unsigned short* p =
          Xb + (rb * 128 + rg * 32 + ri * 16 + lo) * DIM + ks * 32 + hi * 8;
      afrag[ri][ks] = *(const bf16x8*)p;
      asm volatile("" : "+v"(afrag[ri][ks]));  // def-pin: forbid remat
    }
  }

  float mreg[8], ns[8];
#pragma unroll
  for (int ri = 0; ri < 2; ++ri)
#pragma unroll
    for (int reg = 0; reg < 4; ++reg) {
      mreg[ri * 4 + reg] = sdiag[rg * 32 + ri * 16 + hi * 4 + reg];
      ns[ri * 4 + reg] = 0.f;
    }

  // Staging constants: thread t, slot i covers LDS chunk g = i*1024 + t
  // (16B chunks). col = g>>5, ch = g&31; source chunk pre-swizzled: ch^(col&7).
  int srcoff[4];
#pragma unroll
  for (int i = 0; i < 4; ++i) {
    int g = i * 1024 + tid;
    int col = g >> 5, ch = g & 31;
    srcoff[i] = col * DIM + ((ch ^ (col & 7)) << 3);
  }
  const int ldsbase = (wid * 64) << 4;  // + i*16384, wave-uniform

  const unsigned short* astrip = Xb + (size_t)(strip * APS) * NVIEW * DIM;

  // prologue: stage anchor 0 into buf[0]
#pragma unroll
  for (int i = 0; i < 4; ++i)
    gload_lds16(astrip + srcoff[i], (char*)&buf[0][0] + ldsbase + i * 16384);
  __syncthreads();

  const int x8 = lo & 7;
  int cb = 0;
  for (int a = 0; a < APS; ++a) {
    if (a + 1 < APS) {
      const unsigned short* src = astrip + (a + 1) * (NVIEW * DIM);
#pragma unroll
      for (int i = 0; i < 4; ++i)
        gload_lds16(src + srcoff[i], (char*)&buf[cb ^ 1][0] + ldsbase + i * 16384);
    }

    const bool isneg = (slab[strip * APS + a] != myLab);
    const char* bufc = (const char*)&buf[cb][0];
    f32x4 acc[2][2];
#pragma unroll
    for (int ri = 0; ri < 2; ++ri)
#pragma unroll
      for (int ci = 0; ci < 2; ++ci)
        acc[ri][ci] = (f32x4){0.f, 0.f, 0.f, 0.f};

#pragma unroll
    for (int ks = 0; ks < 8; ++ks) {
      const int sw = ((ks * 4 + hi) ^ x8) << 4;
      bf16x8 b0 = *(const bf16x8*)(bufc + (cg * 32 + lo) * 512 + sw);
      bf16x8 b1 = *(const bf16x8*)(bufc + (cg * 32 + 16 + lo) * 512 + sw);
      acc[0][0] = __builtin_amdgcn_mfma_f32_16x16x32_bf16(afrag[0][ks], b0, acc[0][0], 0, 0, 0);
      acc[0][1] = __builtin_amdgcn_mfma_f32_16x16x32_bf16(afrag[0][ks], b1, acc[0][1], 0, 0, 0);
      acc[1][0] = __builtin_amdgcn_mfma_f32_16x16x32_bf16(afrag[1][ks], b0, acc[1][0], 0, 0, 0);
      acc[1][1] = __builtin_amdgcn_mfma_f32_16x16x32_bf16(afrag[1][ks], b1, acc[1][1], 0, 0, 0);
    }

    if (isneg) {
#pragma unroll
      for (int ri = 0; ri < 2; ++ri)
#pragma unroll
        for (int reg = 0; reg < 4; ++reg) {
          const int t = ri * 4 + reg;
          float v0 = acc[ri][0][reg];
          float v1 = acc[ri][1][reg];
          // skip only when the whole pair underflows exp(): exact to fp32+eps
          if (__builtin_expect(fmaxf(v0, v1) > mreg[t] - 40.f, 0))
            ns[t] += __expf(v0 - mreg[t]) + __expf(v1 - mreg[t]);
        }
    }
    __syncthreads();  // staged buffer complete + all reads of buf[cb] done
    cb ^= 1;
  }

  // Sum ns across the 16-lane column groups, then across col-group waves.
#pragma unroll
  for (int t = 0; t < 8; ++t) {
#pragma unroll
    for (int st = 1; st < 16; st <<= 1) ns[t] += __shfl_xor(ns[t], st);
  }
  if (lo == 0) {
#pragma unroll
    for (int ri = 0; ri < 2; ++ri)
#pragma unroll
      for (int reg = 0; reg < 4; ++reg)
        sns[wid][ri * 16 + hi * 4 + reg] = ns[ri * 4 + reg];
  }
  __syncthreads();
  if (tid < 128) {
    const int rg2 = tid >> 5, r32 = tid & 31;
    float s = sns[rg2 * 4 + 0][r32] + sns[rg2 * 4 + 1][r32] +
              sns[rg2 * 4 + 2][r32] + sns[rg2 * 4 + 3][r32];
    ns_partial[strip * N_ROWS + rb * 128 + tid] = s;
  }
}

// -------- Kernel 3: positives pass. 256 blocks x 32 rows, 16 waves
// (col quarter cq x anchor phase bq), B from global (only ~3 anchors/block).
__global__ __launch_bounds__(1024, 4) void pcl_pos(
    const unsigned short* __restrict__ Xb, const int* __restrict__ labels,
    const float* __restrict__ diag, const float* __restrict__ ns_partial,
    float* __restrict__ partials) {
  const int blk = blockIdx.x;
  const int r0 = blk * 32;
  const int tid = threadIdx.x;
  const int wid = tid >> 6;
  const int lane = tid & 63;
  const int lo = lane & 15;
  const int hi = lane >> 4;
  const int cq = wid & 3;
  const int bq = wid >> 2;

  __shared__ int slab[NANCH];
  __shared__ float sred[16][32];
  __shared__ float smf[32];
  __shared__ float snsf[32];
  __shared__ int poslist[NANCH];
  __shared__ int scnt;

  if (tid < NANCH) slab[tid] = labels[tid];
  if (tid >= 64 && tid < 96) {
    int r = tid - 64;
    smf[r] = diag[r0 + r];
    snsf[r] = ns_partial[0 * N_ROWS + r0 + r] + ns_partial[1 * N_ROWS + r0 + r] +
              ns_partial[2 * N_ROWS + r0 + r] + ns_partial[3 * N_ROWS + r0 + r];
  }
  if (tid == 0) {
    int La0 = labels[blk >> 2];
    int c = 0;
    for (int b = 0; b < NANCH; ++b)
      if (labels[b] == La0) poslist[c++] = b;
    scnt = c;
  }
  __syncthreads();

  bf16x8 afrag[2][8];
#pragma unroll
  for (int ri = 0; ri < 2; ++ri) {
#pragma unroll
    for (int ks = 0; ks < 8; ++ks) {
      const unsigned short* p = Xb + (r0 + ri * 16 + lo) * DIM + ks * 32 + hi * 8;
      afrag[ri][ks] = *(const bf16x8*)p;
      asm volatile("" : "+v"(afrag[ri][ks]));
    }
  }

  const int cnt = scnt;
  float pos[8];
#pragma unroll
  for (int t = 0; t < 8; ++t) pos[t] = 0.f;

  for (int p = bq; p < cnt; p += 4) {
    const int b = poslist[p];
    const int c0 = b * NVIEW + cq * 32;
    f32x4 acc[2][2];
#pragma unroll
    for (int ri = 0; ri < 2; ++ri)
#pragma unroll
      for (int ci = 0; ci < 2; ++ci)
        acc[ri][ci] = (f32x4){0.f, 0.f, 0.f, 0.f};

#pragma unroll
    for (int ks = 0; ks < 8; ++ks) {
      bf16x8 b0 = *(const bf16x8*)(Xb + (c0 + lo) * DIM + ks * 32 + hi * 8);
      bf16x8 b1 = *(const bf16x8*)(Xb + (c0 + 16 + lo) * DIM + ks * 32 + hi * 8);
      acc[0][0] = __builtin_amdgcn_mfma_f32_16x16x32_bf16(afrag[0][ks], b0, acc[0][0], 0, 0, 0);
      acc[0][1] = __builtin_amdgcn_mfma_f32_16x16x32_bf16(afrag[0][ks], b1, acc[0][1], 0, 0, 0);
      acc[1][0] = __builtin_amdgcn_mfma_f32_16x16x32_bf16(afrag[1][ks], b0, acc[1][0], 0, 0, 0);
      acc[1][1] = __builtin_amdgcn_mfma_f32_16x16x32_bf16(afrag[1][ks], b1, acc[1][1], 0, 0, 0);
    }

#pragma unroll
    for (int ri = 0; ri < 2; ++ri) {
#pragma unroll
      for (int ci = 0; ci < 2; ++ci) {
#pragma unroll
        for (int reg = 0; reg < 4; ++reg) {
          const int t = ri * 4 + reg;
          const int row = ri * 16 + hi * 4 + reg;
          int grow = r0 + row;
          int gcol = c0 + ci * 16 + lo;
          if (grow != gcol) {
            float d = acc[ri][ci][reg] - smf[row];
            pos[t] += d - __logf(__expf(d) + snsf[row] + 1e-10f);
          }
        }
      }
    }
  }

#pragma unroll
  for (int t = 0; t < 8; ++t) {
#pragma unroll
    for (int st = 1; st < 16; st <<= 1) pos[t] += __shfl_xor(pos[t], st);
  }
  if (lo == 0) {
#pragma unroll
    for (int ri = 0; ri < 2; ++ri)
#pragma unroll
      for (int reg = 0; reg < 4; ++reg)
        sred[wid][ri * 16 + hi * 4 + reg] = pos[ri * 4 + reg];
  }
  __syncthreads();

  const float poscnt = (float)(cnt * NVIEW - 1);
  if (tid < 32) {
    float P = 0.f;
#pragma unroll
    for (int w = 0; w < 16; ++w) P += sred[w][tid];
    smf[tid] = P / poscnt;
  }
  __syncthreads();
  if (tid == 0) {
    float s = 0.f;
    for (int r = 0; r < 32; ++r) s += smf[r];
    partials[blk] = s;
  }
}

__global__ void final_reduce(const float* __restrict__ partials, float* __restrict__ out) {
  __shared__ float s[256];
  int t = threadIdx.x;
  s[t] = partials[t];
  __syncthreads();
  for (int st = 128; st > 0; st >>= 1) {
    if (t < st) s[t] += s[t + st];
    __syncthreads();
  }
  if (t == 0) out[0] = -(0.1f / 0.07f) * s[0] / (float)N_ROWS;
}

extern "C" void kernel_launch(void* const* d_in, const int* in_sizes, int n_in,
                              void* d_out, int out_size, void* d_ws, size_t ws_size,
                              hipStream_t stream) {
  const float* feats = (const float*)d_in[0];
  const int* labels = (const int*)d_in[1];
  float* out = (float*)d_out;

  unsigned short* Xb = (unsigned short*)d_ws;                         // 4 MB
  char* base = (char*)d_ws;
  float* diag = (float*)(base + (size_t)N_ROWS * DIM * 2);            // 32 KB
  float* ns_partial = (float*)(base + (size_t)N_ROWS * DIM * 2 + N_ROWS * 4);  // 128 KB
  float* partials = (float*)(base + (size_t)N_ROWS * DIM * 2 + N_ROWS * 4 +
                             NSTRIP * N_ROWS * 4);

  cast_diag_kernel<<<N_ROWS / 4, 256, 0, stream>>>((const float4v*)feats,
                                                   (ushort4v*)Xb, diag);
  pcl_negsum<<<NANCH * NSTRIP, 1024, 0, stream>>>(Xb, labels, diag, ns_partial);
  pcl_pos<<<N_ROWS / 32, 1024, 0, stream>>>(Xb, labels, diag, ns_partial, partials);
  final_reduce<<<1, 256, 0, stream>>>(partials, out);
}

// Round 5
// 77.366 us; speedup vs baseline: 1.9937x; 1.0251x over previous
//
#include <hip/hip_runtime.h>
#include <hip/hip_bf16.h>

#define N_ROWS 8192
#define DIM 256
#define NANCH 64
#define NVIEW 128
#define NSTRIP 4
#define APS 16      // anchors per strip
#define NPART 8     // column partitions (4 strips x 2 halves)

typedef __attribute__((ext_vector_type(8))) short bf16x8;
typedef __attribute__((ext_vector_type(4))) float f32x4;
typedef __attribute__((ext_vector_type(4))) float float4v;
typedef __attribute__((ext_vector_type(4))) unsigned short ushort4v;

__device__ __forceinline__ unsigned short f2bf(float x) {
  union { float f; unsigned int u; } c; c.f = x;
  unsigned int u = c.u;
  unsigned int r = (u + 0x7fffu + ((u >> 16) & 1u)) >> 16;
  return (unsigned short)r;
}

__device__ __forceinline__ float bf2f(unsigned short b) {
  union { unsigned int u; float f; } c; c.u = ((unsigned int)b) << 16;
  return c.f;
}

__device__ __forceinline__ void gload_lds16(const void* g, void* l) {
  __builtin_amdgcn_global_load_lds(
      (const __attribute__((address_space(1))) unsigned int*)g,
      (__attribute__((address_space(3))) unsigned int*)l, 16, 0, 0);
}

// fp32 -> bf16 with 1/sqrt(T) prescale, fused with per-row squared-norm
// (= the Gram diagonal = the row max of the logits). One wave per row.
__global__ void cast_diag_kernel(const float4v* __restrict__ in,
                                 ushort4v* __restrict__ out,
                                 float* __restrict__ diag) {
  const int w = threadIdx.x >> 6;
  const int l = threadIdx.x & 63;
  const int row = blockIdx.x * 4 + w;
  const float s = 3.16227766016838f; // 1/sqrt(0.1)
  float4v v = in[row * 64 + l];
  ushort4v o;
  o.x = f2bf(v.x * s);
  o.y = f2bf(v.y * s);
  o.z = f2bf(v.z * s);
  o.w = f2bf(v.w * s);
  out[row * 64 + l] = o;
  float c0 = bf2f(o.x), c1 = bf2f(o.y), c2 = bf2f(o.z), c3 = bf2f(o.w);
  float ss = c0 * c0 + c1 * c1 + c2 * c2 + c3 * c3;
#pragma unroll
  for (int st = 1; st < 64; st <<= 1) ss += __shfl_xor(ss, st);
  if (l == 0) diag[row] = ss;
}

// -------- Kernel 2: negative-exp-sum partials over (128 rows x 1024 cols).
// grid = 64 row-blocks x 4 strips x 2 column-halves. 8 waves = 4 row-groups
// x 2 col-groups, 512 threads -> 2 blocks/CU so barrier drains overlap
// across blocks (round-4 was 1 block/CU: whole-CU idle at each barrier).
// 32 KB half-anchor tiles double-buffered; pre-swizzled source so the
// swizzled ds_read_b128 is bank-uniform. Max is KNOWN (= diag): partials
// combine by pure addition.
__global__ __launch_bounds__(512, 4) void pcl_negsum(
    const unsigned short* __restrict__ Xb, const int* __restrict__ labels,
    const float* __restrict__ diag, float* __restrict__ ns_partial) {
  const int rb = blockIdx.x & 63;       // row anchor (128 rows, uniform label)
  const int part = blockIdx.x >> 6;     // 0..7
  const int strip = part >> 1;          // anchors strip*16 .. +15
  const int half = part & 1;            // 64-col half within each anchor
  const int tid = threadIdx.x;
  const int wid = tid >> 6;             // 0..7
  const int lane = tid & 63;
  const int lo = lane & 15;
  const int hi = lane >> 4;
  const int rg = wid >> 1;              // row group (32 rows)
  const int cg = wid & 1;               // col group (32 cols)

  __shared__ unsigned short buf[2][64 * DIM];  // 2 x 32 KB
  __shared__ float sns[8][32];
  __shared__ float sdiag[128];
  __shared__ int slab[NANCH];

  if (tid < NANCH) slab[tid] = labels[tid];
  if (tid >= 128 && tid < 256) sdiag[tid - 128] = diag[rb * 128 + tid - 128];
  __syncthreads();
  const int myLab = slab[rb];

  // A fragments: rows rb*128 + rg*32 + ri*16 + lo, k = ks*32 + hi*8. Pinned.
  bf16x8 afrag[2][8];
#pragma unroll
  for (int ri = 0; ri < 2; ++ri) {
#pragma unroll
    for (int ks = 0; ks < 8; ++ks) {
      const unsigned short* p =
          Xb + (rb * 128 + rg * 32 + ri * 16 + lo) * DIM + ks * 32 + hi * 8;
      afrag[ri][ks] = *(const bf16x8*)p;
      asm volatile("" : "+v"(afrag[ri][ks]));  // def-pin: forbid remat
    }
  }

  float mreg[8], ns[8];
#pragma unroll
  for (int ri = 0; ri < 2; ++ri)
#pragma unroll
    for (int reg = 0; reg < 4; ++reg) {
      mreg[ri * 4 + reg] = sdiag[rg * 32 + ri * 16 + hi * 4 + reg];
      ns[ri * 4 + reg] = 0.f;
    }

  // Staging: thread t, slot i covers LDS chunk g = i*512 + t (16B chunks,
  // 2048 chunks = 32 KB). col = g>>5 (0..63), ch = g&31; source chunk
  // pre-swizzled ch^(col&7) so swizzled read is the same involution.
  int srcoff[4];
#pragma unroll
  for (int i = 0; i < 4; ++i) {
    int g = i * 512 + tid;
    int col = g >> 5, ch = g & 31;
    srcoff[i] = col * DIM + ((ch ^ (col & 7)) << 3);
  }
  const int ldsbase = wid * 1024;  // bytes; + i*8192, wave-uniform

  // source row for anchor a: (strip*APS + a)*NVIEW + half*64
  const unsigned short* asrc0 =
      Xb + ((size_t)(strip * APS) * NVIEW + half * 64) * DIM;

  // prologue: stage anchor 0's half-tile into buf[0]
#pragma unroll
  for (int i = 0; i < 4; ++i)
    gload_lds16(asrc0 + srcoff[i], (char*)&buf[0][0] + ldsbase + i * 8192);
  __syncthreads();

  const int x8 = lo & 7;
  int cb = 0;
  for (int a = 0; a < APS; ++a) {
    if (a + 1 < APS) {
      const unsigned short* src = asrc0 + (size_t)(a + 1) * NVIEW * DIM;
#pragma unroll
      for (int i = 0; i < 4; ++i)
        gload_lds16(src + srcoff[i], (char*)&buf[cb ^ 1][0] + ldsbase + i * 8192);
    }

    const bool isneg = (slab[strip * APS + a] != myLab);
    const char* bufc = (const char*)&buf[cb][0];
    f32x4 acc[2][2];
#pragma unroll
    for (int ri = 0; ri < 2; ++ri)
#pragma unroll
      for (int ci = 0; ci < 2; ++ci)
        acc[ri][ci] = (f32x4){0.f, 0.f, 0.f, 0.f};

#pragma unroll
    for (int ks = 0; ks < 8; ++ks) {
      const int sw = ((ks * 4 + hi) ^ x8) << 4;
      bf16x8 b0 = *(const bf16x8*)(bufc + (cg * 32 + lo) * 512 + sw);
      bf16x8 b1 = *(const bf16x8*)(bufc + (cg * 32 + 16 + lo) * 512 + sw);
      acc[0][0] = __builtin_amdgcn_mfma_f32_16x16x32_bf16(afrag[0][ks], b0, acc[0][0], 0, 0, 0);
      acc[0][1] = __builtin_amdgcn_mfma_f32_16x16x32_bf16(afrag[0][ks], b1, acc[0][1], 0, 0, 0);
      acc[1][0] = __builtin_amdgcn_mfma_f32_16x16x32_bf16(afrag[1][ks], b0, acc[1][0], 0, 0, 0);
      acc[1][1] = __builtin_amdgcn_mfma_f32_16x16x32_bf16(afrag[1][ks], b1, acc[1][1], 0, 0, 0);
    }

    if (isneg) {
#pragma unroll
      for (int ri = 0; ri < 2; ++ri)
#pragma unroll
        for (int reg = 0; reg < 4; ++reg) {
          const int t = ri * 4 + reg;
          float v0 = acc[ri][0][reg];
          float v1 = acc[ri][1][reg];
          // skip only when the whole pair underflows exp(): exact to fp32+eps
          if (__builtin_expect(fmaxf(v0, v1) > mreg[t] - 40.f, 0))
            ns[t] += __expf(v0 - mreg[t]) + __expf(v1 - mreg[t]);
        }
    }
    __syncthreads();  // staged buffer landed + all reads of buf[cb] done
    cb ^= 1;
  }

  // Sum ns across the 16-lane column groups, then across col-group waves.
#pragma unroll
  for (int t = 0; t < 8; ++t) {
#pragma unroll
    for (int st = 1; st < 16; st <<= 1) ns[t] += __shfl_xor(ns[t], st);
  }
  if (lo == 0) {
#pragma unroll
    for (int ri = 0; ri < 2; ++ri)
#pragma unroll
      for (int reg = 0; reg < 4; ++reg)
        sns[wid][ri * 16 + hi * 4 + reg] = ns[ri * 4 + reg];
  }
  __syncthreads();
  if (tid < 128) {
    const int rg2 = tid >> 5, r32 = tid & 31;
    float s = sns[rg2 * 2 + 0][r32] + sns[rg2 * 2 + 1][r32];
    ns_partial[part * N_ROWS + rb * 128 + tid] = s;
  }
}

// -------- Kernel 3: positives pass. 256 blocks x 32 rows, 16 waves
// (col quarter cq x anchor phase bq), B from global (only ~3 anchors/block).
__global__ __launch_bounds__(1024, 4) void pcl_pos(
    const unsigned short* __restrict__ Xb, const int* __restrict__ labels,
    const float* __restrict__ diag, const float* __restrict__ ns_partial,
    float* __restrict__ partials) {
  const int blk = blockIdx.x;
  const int r0 = blk * 32;
  const int tid = threadIdx.x;
  const int wid = tid >> 6;
  const int lane = tid & 63;
  const int lo = lane & 15;
  const int hi = lane >> 4;
  const int cq = wid & 3;
  const int bq = wid >> 2;

  __shared__ int slab[NANCH];
  __shared__ float sred[16][32];
  __shared__ float smf[32];
  __shared__ float snsf[32];
  __shared__ int poslist[NANCH];
  __shared__ int scnt;

  if (tid < NANCH) slab[tid] = labels[tid];
  if (tid >= 64 && tid < 96) {
    int r = tid - 64;
    smf[r] = diag[r0 + r];
    float s = 0.f;
#pragma unroll
    for (int p = 0; p < NPART; ++p) s += ns_partial[p * N_ROWS + r0 + r];
    snsf[r] = s;
  }
  if (tid == 0) {
    int La0 = labels[blk >> 2];
    int c = 0;
    for (int b = 0; b < NANCH; ++b)
      if (labels[b] == La0) poslist[c++] = b;
    scnt = c;
  }
  __syncthreads();

  bf16x8 afrag[2][8];
#pragma unroll
  for (int ri = 0; ri < 2; ++ri) {
#pragma unroll
    for (int ks = 0; ks < 8; ++ks) {
      const unsigned short* p = Xb + (r0 + ri * 16 + lo) * DIM + ks * 32 + hi * 8;
      afrag[ri][ks] = *(const bf16x8*)p;
      asm volatile("" : "+v"(afrag[ri][ks]));
    }
  }

  const int cnt = scnt;
  float pos[8];
#pragma unroll
  for (int t = 0; t < 8; ++t) pos[t] = 0.f;

  for (int p = bq; p < cnt; p += 4) {
    const int b = poslist[p];
    const int c0 = b * NVIEW + cq * 32;
    f32x4 acc[2][2];
#pragma unroll
    for (int ri = 0; ri < 2; ++ri)
#pragma unroll
      for (int ci = 0; ci < 2; ++ci)
        acc[ri][ci] = (f32x4){0.f, 0.f, 0.f, 0.f};

#pragma unroll
    for (int ks = 0; ks < 8; ++ks) {
      bf16x8 b0 = *(const bf16x8*)(Xb + (c0 + lo) * DIM + ks * 32 + hi * 8);
      bf16x8 b1 = *(const bf16x8*)(Xb + (c0 + 16 + lo) * DIM + ks * 32 + hi * 8);
      acc[0][0] = __builtin_amdgcn_mfma_f32_16x16x32_bf16(afrag[0][ks], b0, acc[0][0], 0, 0, 0);
      acc[0][1] = __builtin_amdgcn_mfma_f32_16x16x32_bf16(afrag[0][ks], b1, acc[0][1], 0, 0, 0);
      acc[1][0] = __builtin_amdgcn_mfma_f32_16x16x32_bf16(afrag[1][ks], b0, acc[1][0], 0, 0, 0);
      acc[1][1] = __builtin_amdgcn_mfma_f32_16x16x32_bf16(afrag[1][ks], b1, acc[1][1], 0, 0, 0);
    }

#pragma unroll
    for (int ri = 0; ri < 2; ++ri) {
#pragma unroll
      for (int ci = 0; ci < 2; ++ci) {
#pragma unroll
        for (int reg = 0; reg < 4; ++reg) {
          const int t = ri * 4 + reg;
          const int row = ri * 16 + hi * 4 + reg;
          int grow = r0 + row;
          int gcol = c0 + ci * 16 + lo;
          if (grow != gcol) {
            float d = acc[ri][ci][reg] - smf[row];
            pos[t] += d - __logf(__expf(d) + snsf[row] + 1e-10f);
          }
        }
      }
    }
  }

#pragma unroll
  for (int t = 0; t < 8; ++t) {
#pragma unroll
    for (int st = 1; st < 16; st <<= 1) pos[t] += __shfl_xor(pos[t], st);
  }
  if (lo == 0) {
#pragma unroll
    for (int ri = 0; ri < 2; ++ri)
#pragma unroll
      for (int reg = 0; reg < 4; ++reg)
        sred[wid][ri * 16 + hi * 4 + reg] = pos[ri * 4 + reg];
  }
  __syncthreads();

  const float poscnt = (float)(cnt * NVIEW - 1);
  if (tid < 32) {
    float P = 0.f;
#pragma unroll
    for (int w = 0; w < 16; ++w) P += sred[w][tid];
    smf[tid] = P / poscnt;
  }
  __syncthreads();
  if (tid == 0) {
    float s = 0.f;
    for (int r = 0; r < 32; ++r) s += smf[r];
    partials[blk] = s;
  }
}

__global__ void final_reduce(const float* __restrict__ partials, float* __restrict__ out) {
  __shared__ float s[256];
  int t = threadIdx.x;
  s[t] = partials[t];
  __syncthreads();
  for (int st = 128; st > 0; st >>= 1) {
    if (t < st) s[t] += s[t + st];
    __syncthreads();
  }
  if (t == 0) out[0] = -(0.1f / 0.07f) * s[0] / (float)N_ROWS;
}

extern "C" void kernel_launch(void* const* d_in, const int* in_sizes, int n_in,
                              void* d_out, int out_size, void* d_ws, size_t ws_size,
                              hipStream_t stream) {
  const float* feats = (const float*)d_in[0];
  const int* labels = (const int*)d_in[1];
  float* out = (float*)d_out;

  char* base = (char*)d_ws;
  unsigned short* Xb = (unsigned short*)d_ws;                         // 4 MB
  float* diag = (float*)(base + (size_t)N_ROWS * DIM * 2);            // 32 KB
  float* ns_partial = (float*)(base + (size_t)N_ROWS * DIM * 2 + N_ROWS * 4);  // 256 KB
  float* partials = (float*)(base + (size_t)N_ROWS * DIM * 2 + N_ROWS * 4 +
                             NPART * N_ROWS * 4);

  cast_diag_kernel<<<N_ROWS / 4, 256, 0, stream>>>((const float4v*)feats,
                                                   (ushort4v*)Xb, diag);
  pcl_negsum<<<NANCH * NPART, 512, 0, stream>>>(Xb, labels, diag, ns_partial);
  pcl_pos<<<N_ROWS / 32, 1024, 0, stream>>>(Xb, labels, diag, ns_partial, partials);
  final_reduce<<<1, 256, 0, stream>>>(partials, out);
}